// Round 1
// baseline (193.906 us; speedup 1.0000x reference)
//
#include <hip/hip_runtime.h>
#include <hip/hip_cooperative_groups.h>
#include <math.h>

#define PI_F 3.14159265358979323846f

// ws layout (floats), all slots unconditionally written before read:
//   [0      .. 100352) : partial s  [patch][block]  (196 x 512)
//   [100352 .. 200704) : partial s2 [patch][block]
//   [200704 .. 201096) : final stats float2[196] = (mean, pi/(std+1e-6))
#define PS_OFF  0
#define PS2_OFF 100352
#define ST_OFF  200704

namespace cg = cooperative_groups;

// ---------------------------------------------------------------------------
// Single fused cooperative kernel. 512 blocks x 512 thr, 8 images/block.
// LDS 55.2 KB -> exactly 2 blocks/CU (16 waves/CU), grid==co-resident capacity.
// P0: stage x-tile (reused by BOTH stats and features: x read once) + W.
// P1: per-patch partials from LDS.    grid.sync()
// P2: blocks 0..195 finalize stats.   grid.sync()
// P4: wave-per-image feats + GEMV + log_softmax (circuit reduced analytically:
//     feats = [cos a0, cos a1, cos a0*cos a2, cos a1*cos a3]).
// ---------------------------------------------------------------------------
__global__ __launch_bounds__(512, 4) void k_fused(
    const float* __restrict__ x, const float* __restrict__ W,
    const float* __restrict__ bias, float* __restrict__ ws,
    float* __restrict__ out)
{
    __shared__ __align__(16) float sx[8 * 784];   // 25088 B
    __shared__ __align__(16) float sW[7840];      // 31360 B
    __shared__ float sred[16];
    __shared__ float sbias[10];

    const int tid  = threadIdx.x;
    const int bid  = blockIdx.x;
    const int wave = tid >> 6;
    const int lane = tid & 63;

    // ---- P0: stage this block's 8 images + all of W into LDS ----
    const float4* x4 = (const float4*)(x + (size_t)bid * 8 * 784);
    float4* sx4 = (float4*)sx;
    const float4* W4 = (const float4*)W;
    float4* sW4 = (float4*)sW;
#pragma unroll
    for (int j = 0; j < 3; j++) sx4[tid + j * 512] = x4[tid + j * 512];   // 1536
    if (tid < 32) sx4[1536 + tid] = x4[1536 + tid];                       // 1568
#pragma unroll
    for (int j = 0; j < 3; j++) sW4[tid + j * 512] = W4[tid + j * 512];   // 1536
    if (tid < 424) sW4[1536 + tid] = W4[1536 + tid];                      // 1960
    if (tid < 10) sbias[tid] = bias[tid];
    __syncthreads();

    // ---- P1: per-patch partial (s, s2) over this block's 8 images ----
    if (tid < 196) {
        const int r = tid / 14;
        const int off = 2 * tid + 28 * r;          // even -> 8B aligned
        float s = 0.f, s2 = 0.f;
#pragma unroll
        for (int i = 0; i < 8; i++) {
            const float* bp = sx + i * 784 + off;
            float2 t = *(const float2*)bp;
            float2 u = *(const float2*)(bp + 28);
            s += (t.x + t.y) + (u.x + u.y);
            s2 = fmaf(t.x, t.x, s2); s2 = fmaf(t.y, t.y, s2);
            s2 = fmaf(u.x, u.x, s2); s2 = fmaf(u.y, u.y, s2);
        }
        ws[PS_OFF  + tid * 512 + bid] = s;
        ws[PS2_OFF + tid * 512 + bid] = s2;
    }

    cg::this_grid().sync();

    // ---- P2: blocks 0..195 reduce their patch's 512 partials ----
    if (bid < 196) {
        float s  = ws[PS_OFF  + bid * 512 + tid];   // coalesced row read
        float s2 = ws[PS2_OFF + bid * 512 + tid];
#pragma unroll
        for (int off = 32; off > 0; off >>= 1) {
            s  += __shfl_down(s,  off, 64);
            s2 += __shfl_down(s2, off, 64);
        }
        if (lane == 0) { sred[wave] = s; sred[8 + wave] = s2; }
        __syncthreads();
        if (tid == 0) {
            float S = 0.f, S2 = 0.f;
#pragma unroll
            for (int w = 0; w < 8; w++) { S += sred[w]; S2 += sred[8 + w]; }
            const float N = 16384.0f;
            float mean = S / N;
            float var  = fmaxf((S2 - S * mean) / (N - 1.0f), 0.f);
            ((float2*)(ws + ST_OFF))[bid] =
                make_float2(mean, PI_F / (sqrtf(var) + 1e-6f));
        }
    }

    cg::this_grid().sync();

    // ---- P4: features + GEMV + log_softmax, wave-per-image (LDS x reused) ----
    const float* img = sx + wave * 784;
    const float2* stats = (const float2*)(ws + ST_OFF);   // 1.5 KB, L2/L3-hot

    float acc[10];
#pragma unroll
    for (int o = 0; o < 10; o++) acc[o] = 0.f;

#pragma unroll
    for (int k = 0; k < 4; k++) {
        const int p = lane + 64 * k;
        if (p < 196) {
            const int r = p / 14;
            const int off = 2 * p + 28 * r;
            float2 t = *(const float2*)(img + off);
            float2 u = *(const float2*)(img + off + 28);
            float2 ms = stats[p];
            float c0 = __cosf((t.x - ms.x) * ms.y);
            float c1 = __cosf((t.y - ms.x) * ms.y);
            float f2 = c0 * __cosf((u.x - ms.x) * ms.y);
            float f3 = c1 * __cosf((u.y - ms.x) * ms.y);
            const float* wp = sW + 4 * p;
#pragma unroll
            for (int o = 0; o < 10; o++) {
                float4 w = *(const float4*)(wp + o * 784);
                acc[o] += fmaf(c0, w.x, fmaf(c1, w.y,
                          fmaf(f2, w.z, f3 * w.w)));
            }
        }
    }

#pragma unroll
    for (int o = 0; o < 10; o++) {
#pragma unroll
        for (int off = 32; off > 0; off >>= 1)
            acc[o] += __shfl_down(acc[o], off, 64);
    }

    if (lane == 0) {
        float m = -INFINITY;
#pragma unroll
        for (int o = 0; o < 10; o++) { acc[o] += sbias[o]; m = fmaxf(m, acc[o]); }
        float ssum = 0.f;
#pragma unroll
        for (int o = 0; o < 10; o++) ssum += __expf(acc[o] - m);
        float lse = m + __logf(ssum);
        float* op = out + ((size_t)bid * 8 + wave) * 10;
#pragma unroll
        for (int o = 0; o < 10; o++) op[o] = acc[o] - lse;
    }
}

extern "C" void kernel_launch(void* const* d_in, const int* in_sizes, int n_in,
                              void* d_out, int out_size, void* d_ws, size_t ws_size,
                              hipStream_t stream) {
    const float* x    = (const float*)d_in[0];
    // d_in[1] = params: provably unused (RZ phases cancel in |amp|^2)
    const float* W    = (const float*)d_in[2];
    const float* bias = (const float*)d_in[3];
    float* ws  = (float*)d_ws;
    float* out = (float*)d_out;

    void* args[] = {(void*)&x, (void*)&W, (void*)&bias, (void*)&ws, (void*)&out};
    hipLaunchCooperativeKernel((const void*)k_fused, dim3(512), dim3(512),
                               args, 0, stream);
}

// Round 2
// 88.179 us; speedup vs baseline: 2.1990x; 2.1990x over previous
//
#include <hip/hip_runtime.h>
#include <math.h>

#define PI_F 3.14159265358979323846f

// ws layout (floats), zeroed by a 12.5 KB hipMemsetAsync each launch:
//   [0     .. 1568) : sumS  [8 replicas][196 patches]
//   [1568  .. 3136) : sumS2 [8 replicas][196 patches]
//   [3136]          : arrival counter (uint32)
#define NREP    8
#define S_OFF   0
#define S2_OFF  (NREP * 196)
#define CNT_OFF (2 * NREP * 196)
#define NBLK    256

// ---------------------------------------------------------------------------
// Single fused kernel, custom lightweight grid barrier (no cg::grid_sync —
// that cost ~50us/sync in round 1 doing cross-XCD L2 flushes per block).
// 256 blocks x 512 thr, 16 images/block. LDS 83 KB -> 1 block/CU: grid ==
// CU count, all blocks trivially co-resident for the spin barrier.
// P0: stage x-tile (50KB, used by BOTH stats and features: x read once) + W.
// P1: 392 thr x 8 images partials -> float atomicAdd into 8 global replicas.
// P2: release-increment counter; tid0 spins on agent-scope atomic load.
// P3: all blocks read the 1.5KB sums (agent-scope), finalize stats to LDS.
// P4: wave-per-image feats+GEMV+log_softmax (circuit reduced analytically:
//     feats = [cos a0, cos a1, cos a0*cos a2, cos a1*cos a3]).
// ---------------------------------------------------------------------------
__global__ __launch_bounds__(512, 2) void k_fused(
    const float* __restrict__ x, const float* __restrict__ W,
    const float* __restrict__ bias, float* __restrict__ ws,
    float* __restrict__ out)
{
    __shared__ __align__(16) float  sx[16 * 784];   // 50176 B
    __shared__ __align__(16) float  sW[7840];       // 31360 B
    __shared__ __align__(8)  float2 sst[196];       // 1568 B
    __shared__ float sbias[10];

    const int tid = threadIdx.x;
    const int bid = blockIdx.x;

    // ---- P0: stage this block's 16 images + all of W into LDS ----
    const float4* x4 = (const float4*)(x + (size_t)bid * 16 * 784);
    float4* sx4 = (float4*)sx;
    for (int i = tid; i < 3136; i += 512) sx4[i] = x4[i];
    const float4* W4 = (const float4*)W;
    float4* sW4 = (float4*)sW;
    for (int i = tid; i < 1960; i += 512) sW4[i] = W4[i];
    if (tid < 10) sbias[tid] = bias[tid];
    __syncthreads();

    // ---- P1: per-patch partials (392 thr x 8 images), atomic accumulate ----
    if (tid < 392) {
        const int half = (tid >= 196);
        const int p = tid - 196 * half;
        const int r = p / 14;
        const int off = 2 * p + 28 * r;            // even -> 8B aligned
        const float* base = sx + half * 8 * 784 + off;
        float s = 0.f, s2 = 0.f;
#pragma unroll
        for (int j = 0; j < 8; j++) {
            const float* bp = base + j * 784;
            float2 t = *(const float2*)bp;
            float2 u = *(const float2*)(bp + 28);
            s += (t.x + t.y) + (u.x + u.y);
            s2 = fmaf(t.x, t.x, s2); s2 = fmaf(t.y, t.y, s2);
            s2 = fmaf(u.x, u.x, s2); s2 = fmaf(u.y, u.y, s2);
        }
        const int rep = ((bid << 1) | half) & (NREP - 1);   // 64-way contention
        atomicAdd(ws + S_OFF  + rep * 196 + p, s);
        atomicAdd(ws + S2_OFF + rep * 196 + p, s2);
    }
    __syncthreads();   // drains the atomics (waitcnt before barrier)

    // ---- P2: lightweight grid barrier (4-byte spin, no cache flushes) ----
    if (tid == 0) {
        unsigned* cnt = (unsigned*)(ws + CNT_OFF);
        __hip_atomic_fetch_add(cnt, 1u, __ATOMIC_ACQ_REL,
                               __HIP_MEMORY_SCOPE_AGENT);
        while (__hip_atomic_load(cnt, __ATOMIC_ACQUIRE,
                                 __HIP_MEMORY_SCOPE_AGENT) < NBLK)
            __builtin_amdgcn_s_sleep(2);
    }
    __syncthreads();

    // ---- P3: finalize stats from the 8 replicas (1.5 KB, L2-hot) ----
    if (tid < 196) {
        float S = 0.f, S2 = 0.f;
#pragma unroll
        for (int rp = 0; rp < NREP; rp++) {
            S  += __hip_atomic_load(ws + S_OFF  + rp * 196 + tid,
                                    __ATOMIC_RELAXED, __HIP_MEMORY_SCOPE_AGENT);
            S2 += __hip_atomic_load(ws + S2_OFF + rp * 196 + tid,
                                    __ATOMIC_RELAXED, __HIP_MEMORY_SCOPE_AGENT);
        }
        const float mean = S * (1.0f / 16384.0f);
        const float var  = fmaxf((S2 - S * mean) * (1.0f / 16383.0f), 0.f);
        sst[tid] = make_float2(mean, PI_F / (sqrtf(var) + 1e-6f));
    }
    __syncthreads();

    // ---- P4: feats + GEMV + log_softmax, wave-per-image, 2 images/wave ----
    const int wave = tid >> 6;
    const int lane = tid & 63;

    for (int im = 0; im < 2; im++) {
        const float* img = sx + (wave * 2 + im) * 784;
        float acc[10];
#pragma unroll
        for (int o = 0; o < 10; o++) acc[o] = 0.f;

#pragma unroll
        for (int k = 0; k < 4; k++) {
            const int p = lane + 64 * k;
            if (p < 196) {
                const int r = p / 14;
                const int off = 2 * p + 28 * r;
                float2 t = *(const float2*)(img + off);
                float2 u = *(const float2*)(img + off + 28);
                float2 ms = sst[p];
                float c0 = __cosf((t.x - ms.x) * ms.y);
                float c1 = __cosf((t.y - ms.x) * ms.y);
                float f2 = c0 * __cosf((u.x - ms.x) * ms.y);
                float f3 = c1 * __cosf((u.y - ms.x) * ms.y);
                const float* wp = sW + 4 * p;
#pragma unroll
                for (int o = 0; o < 10; o++) {
                    float4 w = *(const float4*)(wp + o * 784);
                    acc[o] += fmaf(c0, w.x, fmaf(c1, w.y,
                              fmaf(f2, w.z, f3 * w.w)));
                }
            }
        }

#pragma unroll
        for (int o = 0; o < 10; o++) {
#pragma unroll
            for (int sh = 32; sh > 0; sh >>= 1)
                acc[o] += __shfl_down(acc[o], sh, 64);
        }

        if (lane == 0) {
            float m = -INFINITY;
#pragma unroll
            for (int o = 0; o < 10; o++) {
                acc[o] += sbias[o]; m = fmaxf(m, acc[o]);
            }
            float ssum = 0.f;
#pragma unroll
            for (int o = 0; o < 10; o++) ssum += __expf(acc[o] - m);
            const float lse = m + __logf(ssum);
            float* op = out + ((size_t)bid * 16 + wave * 2 + im) * 10;
#pragma unroll
            for (int o = 0; o < 10; o++) op[o] = acc[o] - lse;
        }
    }
}

extern "C" void kernel_launch(void* const* d_in, const int* in_sizes, int n_in,
                              void* d_out, int out_size, void* d_ws, size_t ws_size,
                              hipStream_t stream) {
    const float* x    = (const float*)d_in[0];
    // d_in[1] = params: provably unused (RZ phases cancel in |amp|^2)
    const float* W    = (const float*)d_in[2];
    const float* bias = (const float*)d_in[3];
    float* ws  = (float*)d_ws;
    float* out = (float*)d_out;

    // zero the 12.5 KB accumulator+counter region (graph-capture-safe)
    hipMemsetAsync(d_ws, 0, (2 * NREP * 196 + 1) * sizeof(float), stream);
    hipLaunchKernelGGL(k_fused, dim3(NBLK), dim3(512), 0, stream,
                       x, W, bias, ws, out);
}

// Round 3
// 80.316 us; speedup vs baseline: 2.4143x; 1.0979x over previous
//
#include <hip/hip_runtime.h>
#include <math.h>

#define PI_F 3.14159265358979323846f

// ws layout (floats), zeroed by a 25 KB hipMemsetAsync each launch:
//   [0    .. 3136) : sumS  [16 replicas][196 patches]
//   [3136 .. 6272) : sumS2 [16 replicas][196 patches]
// No spin barrier, no counter: the kernel launch boundary IS the barrier
// (round 1: cg grid.sync = ~50us/sync; round 2: acquire-spin+acq_rel
// barrier = ~25us of cache-maintenance. Kernel boundary: ~1.5us).
#define NREP    16
#define S2_OFF  (NREP * 196)
#define NBLK_A  1024
#define NBLK_B  512

// ---------------------------------------------------------------------------
// Kernel A: per-patch partial stats. 1024 blocks x 4 images, 12.5 KB LDS ->
// 4 blocks/CU = 16 waves/CU (4x round-0 occupancy). Stage images as float4,
// 196 threads reduce their patch in-register over 4 images, then one float
// atomicAdd pair into replica (bid & 15): 64-way contention per address,
// relaxed semantics (HIP default), no fences.
// ---------------------------------------------------------------------------
__global__ __launch_bounds__(256) void k_partial(const float* __restrict__ x,
                                                 float* __restrict__ ws) {
    __shared__ __align__(16) float sx[4 * 784];   // 12544 B
    const float4* x4 = (const float4*)(x + (size_t)blockIdx.x * 4 * 784);
    float4* sx4 = (float4*)sx;
    for (int i = threadIdx.x; i < 784; i += 256) sx4[i] = x4[i];
    __syncthreads();

    const int p = threadIdx.x;
    if (p < 196) {
        const int r = p / 14;
        const int off = 2 * p + 28 * r;            // even -> 8B aligned
        float s = 0.f, s2 = 0.f;
#pragma unroll
        for (int i = 0; i < 4; i++) {
            const float* bp = sx + i * 784 + off;
            float2 t = *(const float2*)bp;
            float2 u = *(const float2*)(bp + 28);
            s += (t.x + t.y) + (u.x + u.y);
            s2 = fmaf(t.x, t.x, s2); s2 = fmaf(t.y, t.y, s2);
            s2 = fmaf(u.x, u.x, s2); s2 = fmaf(u.y, u.y, s2);
        }
        const int rep = blockIdx.x & (NREP - 1);
        atomicAdd(ws + rep * 196 + p, s);
        atomicAdd(ws + S2_OFF + rep * 196 + p, s2);
    }
}

// ---------------------------------------------------------------------------
// Kernel B: stats finalize (inline, from 16 replicas — kernel boundary makes
// A's atomics visible to plain loads) + features + GEMV + log_softmax.
// 512 blocks x 512 thr, 8 images/block (1/wave), 58 KB LDS -> 2 blocks/CU,
// 16 waves/CU. Circuit reduced analytically (RZ phases cancel in |amp|^2;
// CNOTs permute basis): feats = [cos a0, cos a1, cos a0*cos a2, cos a1*cos a3].
// x re-read hits LLC (staged there by kernel A this iteration).
// ---------------------------------------------------------------------------
__global__ __launch_bounds__(512, 4) void k_main(const float* __restrict__ x,
                                                 const float* __restrict__ W,
                                                 const float* __restrict__ bias,
                                                 const float* __restrict__ ws,
                                                 float* __restrict__ out) {
    __shared__ __align__(16) float  sW[7840];     // raw W [10][784]
    __shared__ __align__(16) float  sx[8 * 784];
    __shared__ __align__(8)  float2 sst[196];
    __shared__ float sbias[10];

    const int tid = threadIdx.x;
    const float4* W4 = (const float4*)W;
    for (int i = tid; i < 1960; i += 512)
        ((float4*)sW)[i] = W4[i];
    const float4* x4 = (const float4*)(x + (size_t)blockIdx.x * 8 * 784);
    for (int i = tid; i < 1568; i += 512)
        ((float4*)sx)[i] = x4[i];
    if (tid < 196) {
        float S = 0.f, S2 = 0.f;
#pragma unroll
        for (int rp = 0; rp < NREP; rp++) {        // coalesced per-rep rows
            S  += ws[rp * 196 + tid];
            S2 += ws[S2_OFF + rp * 196 + tid];
        }
        const float mean = S * (1.0f / 16384.0f);
        const float var  = fmaxf((S2 - S * mean) * (1.0f / 16383.0f), 0.f);
        sst[tid] = make_float2(mean, PI_F / (sqrtf(var) + 1e-6f));
    }
    if (tid < 10) sbias[tid] = bias[tid];
    __syncthreads();

    const int wave = tid >> 6;
    const int lane = tid & 63;
    const float* img = sx + wave * 784;

    float acc[10];
#pragma unroll
    for (int o = 0; o < 10; o++) acc[o] = 0.f;

#pragma unroll
    for (int k = 0; k < 4; k++) {
        const int p = lane + 64 * k;
        if (p < 196) {
            const int r = p / 14;
            const int off = 2 * p + 28 * r;
            float2 t = *(const float2*)(img + off);
            float2 u = *(const float2*)(img + off + 28);
            float2 ms = sst[p];
            float c0 = __cosf((t.x - ms.x) * ms.y);
            float c1 = __cosf((t.y - ms.x) * ms.y);
            float f2 = c0 * __cosf((u.x - ms.x) * ms.y);
            float f3 = c1 * __cosf((u.y - ms.x) * ms.y);
            const float* wp = sW + 4 * p;
#pragma unroll
            for (int o = 0; o < 10; o++) {
                float4 w = *(const float4*)(wp + o * 784);
                acc[o] += fmaf(c0, w.x, fmaf(c1, w.y,
                          fmaf(f2, w.z, f3 * w.w)));
            }
        }
    }

#pragma unroll
    for (int o = 0; o < 10; o++) {
#pragma unroll
        for (int sh = 32; sh > 0; sh >>= 1)
            acc[o] += __shfl_down(acc[o], sh, 64);
    }

    if (lane == 0) {
        float m = -INFINITY;
#pragma unroll
        for (int o = 0; o < 10; o++) { acc[o] += sbias[o]; m = fmaxf(m, acc[o]); }
        float ssum = 0.f;
#pragma unroll
        for (int o = 0; o < 10; o++) ssum += __expf(acc[o] - m);
        const float lse = m + __logf(ssum);
        float* op = out + ((size_t)blockIdx.x * 8 + wave) * 10;
#pragma unroll
        for (int o = 0; o < 10; o++) op[o] = acc[o] - lse;
    }
}

extern "C" void kernel_launch(void* const* d_in, const int* in_sizes, int n_in,
                              void* d_out, int out_size, void* d_ws, size_t ws_size,
                              hipStream_t stream) {
    const float* x    = (const float*)d_in[0];
    // d_in[1] = params: provably unused (RZ phases cancel in |amp|^2)
    const float* W    = (const float*)d_in[2];
    const float* bias = (const float*)d_in[3];
    float* ws  = (float*)d_ws;
    float* out = (float*)d_out;

    // zero the 25 KB replica accumulators (graph-capture-safe)
    hipMemsetAsync(d_ws, 0, 2 * NREP * 196 * sizeof(float), stream);
    hipLaunchKernelGGL(k_partial, dim3(NBLK_A), dim3(256), 0, stream, x, ws);
    hipLaunchKernelGGL(k_main,    dim3(NBLK_B), dim3(512), 0, stream,
                       x, W, bias, ws, out);
}

// Round 4
// 76.742 us; speedup vs baseline: 2.5267x; 1.0466x over previous
//
#include <hip/hip_runtime.h>
#include <math.h>

#define PI_F 3.14159265358979323846f

// ws layout (floats), zeroed by a 25 KB hipMemsetAsync each launch:
//   [0    .. 3136) : sumS  [16 replicas][196 patches]
//   [3136 .. 6272) : sumS2 [16 replicas][196 patches]
// Kernel launch boundary = the grid barrier (round 1: cg sync ~50us/sync;
// round 2: acquire-spin ~+8us; round 3: boundary = best).
#define NREP    16
#define S2_OFF  (NREP * 196)
#define NBLK_A  512
#define NBLK_B  512

// ---------------------------------------------------------------------------
// Kernel A: per-patch partial stats. 512 blocks x 8 images, 25 KB LDS.
// Stage images as float4 (coalesced; warms LLC for kernel B), 196 threads
// reduce their patch over 8 images, one atomicAdd pair into replica
// (bid & 15): 32 adds/address, relaxed, no fences. 200K atomics total
// (half of round 3).
// ---------------------------------------------------------------------------
__global__ __launch_bounds__(256) void k_partial(const float* __restrict__ x,
                                                 float* __restrict__ ws) {
    __shared__ __align__(16) float sx[8 * 784];   // 25088 B
    const float4* x4 = (const float4*)(x + (size_t)blockIdx.x * 8 * 784);
    float4* sx4 = (float4*)sx;
    const int tid = threadIdx.x;
#pragma unroll
    for (int j = 0; j < 6; j++) sx4[tid + j * 256] = x4[tid + j * 256]; // 1536
    if (tid < 32) sx4[1536 + tid] = x4[1536 + tid];                     // 1568
    __syncthreads();

    const int p = tid;
    if (p < 196) {
        const int r = p / 14;
        const int off = 2 * p + 28 * r;            // even -> 8B aligned
        float s = 0.f, s2 = 0.f;
#pragma unroll
        for (int i = 0; i < 8; i++) {
            const float* bp = sx + i * 784 + off;
            float2 t = *(const float2*)bp;
            float2 u = *(const float2*)(bp + 28);
            s += (t.x + t.y) + (u.x + u.y);
            s2 = fmaf(t.x, t.x, s2); s2 = fmaf(t.y, t.y, s2);
            s2 = fmaf(u.x, u.x, s2); s2 = fmaf(u.y, u.y, s2);
        }
        const int rep = blockIdx.x & (NREP - 1);
        atomicAdd(ws + rep * 196 + p, s);
        atomicAdd(ws + S2_OFF + rep * 196 + p, s2);
    }
}

// ---------------------------------------------------------------------------
// Kernel B: stats finalize (from 16 replicas; kernel boundary makes A's
// atomics visible to plain loads) + features + GEMV + log_softmax.
// 512 blocks x 512 thr, 1 image/wave. x is NOT staged to LDS: each pixel is
// consumed exactly once by exactly one wave (zero reuse) and x is LLC-hot
// from kernel A — per-lane float2 global loads instead. LDS = W + stats
// (33 KB, was 58 KB), one less __syncthreads on the critical path.
// Circuit reduced analytically (RZ phases cancel in |amp|^2; CNOTs permute
// basis): feats = [cos a0, cos a1, cos a0*cos a2, cos a1*cos a3].
// ---------------------------------------------------------------------------
__global__ __launch_bounds__(512, 4) void k_main(const float* __restrict__ x,
                                                 const float* __restrict__ W,
                                                 const float* __restrict__ bias,
                                                 const float* __restrict__ ws,
                                                 float* __restrict__ out) {
    __shared__ __align__(16) float  sW[7840];     // raw W [10][784]
    __shared__ __align__(8)  float2 sst[196];
    __shared__ float sbias[10];

    const int tid = threadIdx.x;
    const float4* W4 = (const float4*)W;
    float4* sW4 = (float4*)sW;
#pragma unroll
    for (int j = 0; j < 3; j++) sW4[tid + j * 512] = W4[tid + j * 512]; // 1536
    if (tid < 424) sW4[1536 + tid] = W4[1536 + tid];                    // 1960
    if (tid < 196) {
        float S = 0.f, S2 = 0.f;
#pragma unroll
        for (int rp = 0; rp < NREP; rp++) {        // coalesced 4B rows
            S  += ws[rp * 196 + tid];
            S2 += ws[S2_OFF + rp * 196 + tid];
        }
        const float mean = S * (1.0f / 16384.0f);
        const float var  = fmaxf((S2 - S * mean) * (1.0f / 16383.0f), 0.f);
        sst[tid] = make_float2(mean, PI_F / (sqrtf(var) + 1e-6f));
    }
    if (tid < 10) sbias[tid] = bias[tid];
    __syncthreads();

    const int wave = tid >> 6;
    const int lane = tid & 63;
    const float* img = x + ((size_t)blockIdx.x * 8 + wave) * 784;  // LLC-hot

    float acc[10];
#pragma unroll
    for (int o = 0; o < 10; o++) acc[o] = 0.f;

#pragma unroll
    for (int k = 0; k < 4; k++) {
        const int p = lane + 64 * k;
        if (p < 196) {
            const int r = p / 14;
            const int off = 2 * p + 28 * r;        // even -> 8B aligned
            float2 t = *(const float2*)(img + off);
            float2 u = *(const float2*)(img + off + 28);
            float2 ms = sst[p];
            float c0 = __cosf((t.x - ms.x) * ms.y);
            float c1 = __cosf((t.y - ms.x) * ms.y);
            float f2 = c0 * __cosf((u.x - ms.x) * ms.y);
            float f3 = c1 * __cosf((u.y - ms.x) * ms.y);
            const float* wp = sW + 4 * p;
#pragma unroll
            for (int o = 0; o < 10; o++) {
                float4 w = *(const float4*)(wp + o * 784);
                acc[o] += fmaf(c0, w.x, fmaf(c1, w.y,
                          fmaf(f2, w.z, f3 * w.w)));
            }
        }
    }

#pragma unroll
    for (int o = 0; o < 10; o++) {
#pragma unroll
        for (int sh = 32; sh > 0; sh >>= 1)
            acc[o] += __shfl_down(acc[o], sh, 64);
    }

    if (lane == 0) {
        float m = -INFINITY;
#pragma unroll
        for (int o = 0; o < 10; o++) { acc[o] += sbias[o]; m = fmaxf(m, acc[o]); }
        float ssum = 0.f;
#pragma unroll
        for (int o = 0; o < 10; o++) ssum += __expf(acc[o] - m);
        const float lse = m + __logf(ssum);
        float* op = out + ((size_t)blockIdx.x * 8 + wave) * 10;
#pragma unroll
        for (int o = 0; o < 10; o++) op[o] = acc[o] - lse;
    }
}

extern "C" void kernel_launch(void* const* d_in, const int* in_sizes, int n_in,
                              void* d_out, int out_size, void* d_ws, size_t ws_size,
                              hipStream_t stream) {
    const float* x    = (const float*)d_in[0];
    // d_in[1] = params: provably unused (RZ phases cancel in |amp|^2)
    const float* W    = (const float*)d_in[2];
    const float* bias = (const float*)d_in[3];
    float* ws  = (float*)d_ws;
    float* out = (float*)d_out;

    // zero the 25 KB replica accumulators (graph-capture-safe)
    hipMemsetAsync(d_ws, 0, 2 * NREP * 196 * sizeof(float), stream);
    hipLaunchKernelGGL(k_partial, dim3(NBLK_A), dim3(256), 0, stream, x, ws);
    hipLaunchKernelGGL(k_main,    dim3(NBLK_B), dim3(512), 0, stream,
                       x, W, bias, ws, out);
}